// Round 1
// baseline (191.468 us; speedup 1.0000x reference)
//
#include <hip/hip_runtime.h>
#include <math.h>

#define CCH 256
#define HH  96
#define WW  96
#define HW  9216      // H*W
#define CW  24576     // C*W (columns of the [96, 24576] reshape)
#define TWO_PI 6.28318530717958647692f

// ---------------- Kernel 1: per-channel min / max of |x| ----------------
__global__ __launch_bounds__(256) void k_minmax(const float* __restrict__ x,
                                                float* __restrict__ mn,
                                                float* __restrict__ mx) {
    int c = blockIdx.x;
    const float* p = x + c * HW;
    float lo = 1e30f, hi = -1e30f;
    for (int i = threadIdx.x; i < HW; i += 256) {
        float a = fabsf(p[i]);
        lo = fminf(lo, a);
        hi = fmaxf(hi, a);
    }
    __shared__ float slo[256], shi[256];
    slo[threadIdx.x] = lo; shi[threadIdx.x] = hi;
    __syncthreads();
    for (int s = 128; s > 0; s >>= 1) {
        if (threadIdx.x < s) {
            slo[threadIdx.x] = fminf(slo[threadIdx.x], slo[threadIdx.x + s]);
            shi[threadIdx.x] = fmaxf(shi[threadIdx.x], shi[threadIdx.x + s]);
        }
        __syncthreads();
    }
    if (threadIdx.x == 0) { mn[c] = slo[0]; mx[c] = shi[0]; }
}

// ---------------- Kernel 2: 16-coefficient DFT band-pass per channel ----------------
// Kept frequencies (after un-fftshift): ky,kx in {-2,-1,0,1}  (index k = idx-2)
// FQ[y,x] = | (1/9216) * sum_{ky,kx} F[ky,kx] e^{+2πi(ky*y+kx*x)/96} |
__global__ void k_freq(const float* __restrict__ x,
                       const float* __restrict__ mn,
                       const float* __restrict__ mx,
                       float* __restrict__ FQ) {
    int c = blockIdx.x;
    int t = threadIdx.x;            // 0..95, one column per thread
    __shared__ float cs[96][2];     // cos/sin(2π t/96)
    __shared__ float Gs[4][96][2];  // per-column y-DFT, k index 0..3 -> k=-2..1
    __shared__ float Fs[4][4][2];   // the 16 coefficients

    float ang = TWO_PI * (float)t / 96.0f;
    cs[t][0] = cosf(ang);
    cs[t][1] = sinf(ang);
    __syncthreads();

    float m0 = mn[c];
    float pt = mx[c] - m0;
    const float* xp = x + c * HW;

    // Phase A: G[k, x=t] = sum_y q[y,t] * e^{-2πi k y/96}
    // k=-2 -> e^{+2iθ}, k=-1 -> e^{+iθ}, k=0 -> 1, k=+1 = conj(k=-1)
    float g0r = 0.f, g0i = 0.f, g1r = 0.f, g1i = 0.f, g2 = 0.f;
    for (int y = 0; y < 96; ++y) {
        float a = fabsf(xp[y * 96 + t]);
        float q = floorf(255.0f * (a - m0) / pt);
        float c1 = cs[y][0], s1 = cs[y][1];
        float c2 = c1 * c1 - s1 * s1, s2 = 2.0f * c1 * s1;
        g0r += q * c2; g0i += q * s2;
        g1r += q * c1; g1i += q * s1;
        g2  += q;
    }
    Gs[0][t][0] = g0r; Gs[0][t][1] = g0i;
    Gs[1][t][0] = g1r; Gs[1][t][1] = g1i;
    Gs[2][t][0] = g2;  Gs[2][t][1] = 0.f;
    Gs[3][t][0] = g1r; Gs[3][t][1] = -g1i;
    __syncthreads();

    // Phase A2: F[ky,kx] = sum_x G[ky,x] * e^{-2πi (kx-2) x/96}
    if (t < 16) {
        int ky = t >> 2, kx = t & 3;
        float fr = 0.f, fi = 0.f;
        for (int xx = 0; xx < 96; ++xx) {
            float c1 = cs[xx][0], s1 = cs[xx][1];
            float er, ei;
            if (kx == 0)      { er = c1 * c1 - s1 * s1; ei = 2.0f * c1 * s1; } // k=-2: e^{+2iθ}
            else if (kx == 1) { er = c1; ei = s1;  }                           // k=-1: e^{+iθ}
            else if (kx == 2) { er = 1.f; ei = 0.f; }                          // k=0
            else              { er = c1; ei = -s1; }                           // k=+1: e^{-iθ}
            float gr = Gs[ky][xx][0], gi = Gs[ky][xx][1];
            fr += gr * er - gi * ei;
            fi += gr * ei + gi * er;
        }
        Fs[ky][kx][0] = fr; Fs[ky][kx][1] = fi;
    }
    __syncthreads();

    // Phase B: synthesis. T[kx] = e^{+2πi (kx-2) t/96}
    float c1 = cs[t][0], s1 = cs[t][1];
    float c2 = c1 * c1 - s1 * s1, s2 = 2.0f * c1 * s1;
    float Tr[4] = { c2, c1, 1.f, c1 };
    float Ti[4] = { -s2, -s1, 0.f, s1 };
    float Pr[4], Pi[4];
    #pragma unroll
    for (int ky = 0; ky < 4; ++ky) {
        float pr = 0.f, pi = 0.f;
        #pragma unroll
        for (int kx = 0; kx < 4; ++kx) {
            float fr = Fs[ky][kx][0], fi = Fs[ky][kx][1];
            pr += fr * Tr[kx] - fi * Ti[kx];
            pi += fr * Ti[kx] + fi * Tr[kx];
        }
        Pr[ky] = pr; Pi[ky] = pi;
    }
    float* outp = FQ + c * HW;
    const float inv = 1.0f / 9216.0f;
    for (int y = 0; y < 96; ++y) {
        float cy = cs[y][0], sy = cs[y][1];
        float cy2 = cy * cy - sy * sy, sy2 = 2.0f * cy * sy;
        // U[ky]: ky=0 -> (cy2,-sy2), 1 -> (cy,-sy), 2 -> (1,0), 3 -> (cy,sy)
        float ar = Pr[0] * cy2 + Pi[0] * sy2
                 + Pr[1] * cy  + Pi[1] * sy
                 + Pr[2]
                 + Pr[3] * cy  - Pi[3] * sy;
        float ai = -Pr[0] * sy2 + Pi[0] * cy2
                 -  Pr[1] * sy  + Pi[1] * cy
                 +  Pi[2]
                 +  Pr[3] * sy  + Pi[3] * cy;
        outp[y * 96 + t] = sqrtf(ar * ar + ai * ai) * inv;
    }
}

// ---------------- Kernel 3/5: conv1x1 GEMM: out[o,p] = sum_c W[o,c] X[c,p] + b[o] ----------------
// grid (36, 16): 256 pixels per block.x, 16 output channels per block.y
template<bool APPLY_MASK>
__global__ __launch_bounds__(256) void k_gemm(const float* __restrict__ X,
                                              const float* __restrict__ Wm,
                                              const float* __restrict__ bias,
                                              const float* __restrict__ mask,
                                              float* __restrict__ out) {
    int p  = blockIdx.x * 256 + threadIdx.x;
    int ob = blockIdx.y * 16;
    __shared__ float Wl[256 * 16];  // layout [c][j], j contiguous -> float4 broadcast reads
    #pragma unroll
    for (int m = 0; m < 16; ++m)
        Wl[threadIdx.x * 16 + m] = Wm[(ob + m) * 256 + threadIdx.x];
    __syncthreads();

    float acc[16];
    #pragma unroll
    for (int j = 0; j < 16; ++j) acc[j] = 0.f;

    const float4* W4 = (const float4*)Wl;
    #pragma unroll 4
    for (int c = 0; c < 256; ++c) {
        float xv = X[c * HW + p];
        float4 w0 = W4[c * 4 + 0];
        float4 w1 = W4[c * 4 + 1];
        float4 w2 = W4[c * 4 + 2];
        float4 w3 = W4[c * 4 + 3];
        acc[0]  += w0.x * xv; acc[1]  += w0.y * xv; acc[2]  += w0.z * xv; acc[3]  += w0.w * xv;
        acc[4]  += w1.x * xv; acc[5]  += w1.y * xv; acc[6]  += w1.z * xv; acc[7]  += w1.w * xv;
        acc[8]  += w2.x * xv; acc[9]  += w2.y * xv; acc[10] += w2.z * xv; acc[11] += w2.w * xv;
        acc[12] += w3.x * xv; acc[13] += w3.y * xv; acc[14] += w3.z * xv; acc[15] += w3.w * xv;
    }

    #pragma unroll
    for (int j = 0; j < 16; ++j) {
        int o = ob + j;
        float v = acc[j] + bias[o];
        if (APPLY_MASK) {
            // mask index = (o*9216 + p) mod 24576 = ((o&7)*9216 + p) mod 24576
            int k = (o & 7) * HW + p;
            if (k >= CW) k -= CW;
            if (k >= CW) k -= CW;
            v = v * (1.0f + mask[k]);
        }
        out[o * HW + p] = v;
    }
}

// ---------------- Kernel 4: FQmax[k] = max_{r<96} Q_flat[r*24576 + k] ----------------
__global__ __launch_bounds__(256) void k_colmax(const float* __restrict__ Q,
                                                float* __restrict__ mx) {
    int k = blockIdx.x * 256 + threadIdx.x;
    float m = -1e30f;
    #pragma unroll 4
    for (int r = 0; r < 96; ++r)
        m = fmaxf(m, Q[r * CW + k]);
    mx[k] = m;
}

extern "C" void kernel_launch(void* const* d_in, const int* in_sizes, int n_in,
                              void* d_out, int out_size, void* d_ws, size_t ws_size,
                              hipStream_t stream) {
    const float* fuse = (const float*)d_in[0];
    const float* Wq   = (const float*)d_in[1];
    const float* bq   = (const float*)d_in[2];
    // d_in[3]=Wk, d_in[4]=bk are dead code for B=1 (softmax over batch axis of size 1 == 1.0)
    const float* Wv   = (const float*)d_in[5];
    const float* bv   = (const float*)d_in[6];
    float* out = (float*)d_out;

    float* ws    = (float*)d_ws;
    float* mn    = ws;                 // 256
    float* mx    = ws + 256;           // 256
    float* FQmax = ws + 512;           // 24576
    float* FQ    = ws + 512 + CW;      // 2359296
    float* Q     = out;                // reuse d_out as scratch for the Q GEMM (exactly 2359296 floats)

    k_minmax<<<256, 256, 0, stream>>>(fuse, mn, mx);
    k_freq<<<256, 96, 0, stream>>>(fuse, mn, mx, FQ);
    k_gemm<false><<<dim3(36, 16), 256, 0, stream>>>(FQ, Wq, bq, nullptr, Q);
    k_colmax<<<96, 256, 0, stream>>>(Q, FQmax);
    k_gemm<true><<<dim3(36, 16), 256, 0, stream>>>(fuse, Wv, bv, FQmax, out);
}